// Round 1
// baseline (727.027 us; speedup 1.0000x reference)
//
#include <hip/hip_runtime.h>

#define N_NODES 100000
#define N_EDGES 1600000
#define D_FEAT 32

// One thread per (edge, float4-slice-of-8). 8 threads cover one edge's 32 feats.
__global__ __launch_bounds__(256) void lgc_scatter(
    const float4* __restrict__ src_feats4,   // [N_NODES * 8]
    const float*  __restrict__ cj,           // [N_NODES]
    const int*    __restrict__ src_idx,      // [N_EDGES]
    const int*    __restrict__ dst_idx,      // [N_EDGES]
    float*        __restrict__ out)          // [N_NODES * 32]
{
    long tid = (long)blockIdx.x * blockDim.x + threadIdx.x;
    const long total = (long)N_EDGES * 8;
    if (tid >= total) return;

    int e  = (int)(tid >> 3);
    int f4 = (int)(tid & 7);

    int s = src_idx[e];
    int d = dst_idx[e];
    float c = cj[s];

    float4 v = src_feats4[s * 8 + f4];

    float* o = out + (size_t)d * D_FEAT + f4 * 4;
    atomicAdd(o + 0, v.x * c);
    atomicAdd(o + 1, v.y * c);
    atomicAdd(o + 2, v.z * c);
    atomicAdd(o + 3, v.w * c);
}

// out[n][:] *= ci[n], float4-vectorized: 8 float4 per node.
__global__ __launch_bounds__(256) void lgc_scale(
    float4*       __restrict__ out4,   // [N_NODES * 8]
    const float*  __restrict__ ci)     // [N_NODES]
{
    int tid = blockIdx.x * blockDim.x + threadIdx.x;
    const int total = N_NODES * 8;
    if (tid >= total) return;

    float c = ci[tid >> 3];
    float4 v = out4[tid];
    v.x *= c; v.y *= c; v.z *= c; v.w *= c;
    out4[tid] = v;
}

extern "C" void kernel_launch(void* const* d_in, const int* in_sizes, int n_in,
                              void* d_out, int out_size, void* d_ws, size_t ws_size,
                              hipStream_t stream) {
    const float4* src_feats4 = (const float4*)d_in[0];  // [100000, 32] f32
    const float*  cj         = (const float*)d_in[1];   // [100000, 1]
    const float*  ci         = (const float*)d_in[2];   // [100000, 1]
    const int*    src_idx    = (const int*)d_in[3];     // [1600000]
    const int*    dst_idx    = (const int*)d_in[4];     // [1600000]
    float*        out        = (float*)d_out;           // [100000, 32] f32

    // Zero the accumulator (harness poisons d_out with 0xAA).
    hipMemsetAsync(d_out, 0, (size_t)out_size * sizeof(float), stream);

    {
        const long total = (long)N_EDGES * 8;   // 12.8M work items
        const int block = 256;
        const int grid = (int)((total + block - 1) / block);
        lgc_scatter<<<grid, block, 0, stream>>>(src_feats4, cj, src_idx, dst_idx, out);
    }
    {
        const int total = N_NODES * 8;          // 800k float4 items
        const int block = 256;
        const int grid = (total + block - 1) / block;
        lgc_scale<<<grid, block, 0, stream>>>((float4*)d_out, ci);
    }
}

// Round 2
// 289.425 us; speedup vs baseline: 2.5120x; 2.5120x over previous
//
#include <hip/hip_runtime.h>

#define N_NODES 100000
#define N_EDGES 1600000
#define D_FEAT 32
#define CAP 64                      // bucket capacity per node; Poisson(16) max deg ~45

// ---------------- bucket build: 1.6M returning int atomics ----------------
__global__ __launch_bounds__(256) void lgc_bucket(
    const int*   __restrict__ src_idx,
    const int*   __restrict__ dst_idx,
    const float* __restrict__ src_feats,
    const float* __restrict__ cj,
    int*         __restrict__ cnt,      // [N_NODES], pre-zeroed
    int*         __restrict__ bucket,   // [N_NODES * CAP]
    float*       __restrict__ out)      // pre-zeroed; overflow spill target
{
    int e = blockIdx.x * 256 + threadIdx.x;
    if (e >= N_EDGES) return;
    int s = src_idx[e];
    int d = dst_idx[e];
    int pos = atomicAdd(&cnt[d], 1);
    if (pos < CAP) {
        bucket[(size_t)d * CAP + pos] = s;
    } else {
        // overflow fallback (statistically never taken; correctness safety)
        float c = cj[s];
        const float* row = src_feats + (size_t)s * D_FEAT;
        float* o = out + (size_t)d * D_FEAT;
        for (int f = 0; f < D_FEAT; ++f) atomicAdd(o + f, row[f] * c);
    }
}

// ---------------- gather-sum: thread = (node, feat), no atomics ----------------
__global__ __launch_bounds__(256) void lgc_gather(
    const float* __restrict__ src_feats,
    const float* __restrict__ cj,
    const float* __restrict__ ci,
    const int*   __restrict__ cnt,
    const int*   __restrict__ bucket,
    float*       __restrict__ out)
{
    int tid = blockIdx.x * 256 + threadIdx.x;   // grid is exact: 3.2M threads
    int n = tid >> 5;
    int f = tid & 31;

    int c = cnt[n];
    if (c > CAP) c = CAP;
    const int* b = bucket + (size_t)n * CAP;

    float acc = 0.f;
    for (int i = 0; i < c; ++i) {
        int s = b[i];                                  // broadcast across 32 lanes
        acc += src_feats[(size_t)s * D_FEAT + f] * cj[s];  // 128B coalesced row
    }
    // out holds overflow spill (pre-zeroed, usually 0); scale everything by ci
    out[tid] = (out[tid] + acc) * ci[n];
}

// ---------------- round-1 fallback path (used only if ws too small) ----------------
__global__ __launch_bounds__(256) void lgc_scatter(
    const float4* __restrict__ src_feats4,
    const float*  __restrict__ cj,
    const int*    __restrict__ src_idx,
    const int*    __restrict__ dst_idx,
    float*        __restrict__ out)
{
    long tid = (long)blockIdx.x * blockDim.x + threadIdx.x;
    const long total = (long)N_EDGES * 8;
    if (tid >= total) return;
    int e  = (int)(tid >> 3);
    int f4 = (int)(tid & 7);
    int s = src_idx[e];
    int d = dst_idx[e];
    float c = cj[s];
    float4 v = src_feats4[s * 8 + f4];
    float* o = out + (size_t)d * D_FEAT + f4 * 4;
    atomicAdd(o + 0, v.x * c);
    atomicAdd(o + 1, v.y * c);
    atomicAdd(o + 2, v.z * c);
    atomicAdd(o + 3, v.w * c);
}

__global__ __launch_bounds__(256) void lgc_scale(
    float4*       __restrict__ out4,
    const float*  __restrict__ ci)
{
    int tid = blockIdx.x * blockDim.x + threadIdx.x;
    const int total = N_NODES * 8;
    if (tid >= total) return;
    float c = ci[tid >> 3];
    float4 v = out4[tid];
    v.x *= c; v.y *= c; v.z *= c; v.w *= c;
    out4[tid] = v;
}

extern "C" void kernel_launch(void* const* d_in, const int* in_sizes, int n_in,
                              void* d_out, int out_size, void* d_ws, size_t ws_size,
                              hipStream_t stream) {
    const float* src_feats = (const float*)d_in[0];   // [100000, 32] f32
    const float* cj        = (const float*)d_in[1];   // [100000, 1]
    const float* ci        = (const float*)d_in[2];   // [100000, 1]
    const int*   src_idx   = (const int*)d_in[3];     // [1600000]
    const int*   dst_idx   = (const int*)d_in[4];     // [1600000]
    float*       out       = (float*)d_out;           // [100000, 32] f32

    // ws layout: cnt[102400 ints] | bucket[N_NODES*CAP ints]
    const size_t cnt_ints    = 102400;                    // 400KB, 256B-aligned pad
    const size_t bucket_ints = (size_t)N_NODES * CAP;     // 25.6 MB
    const size_t need = (cnt_ints + bucket_ints) * sizeof(int);

    if (ws_size >= need) {
        int* cnt    = (int*)d_ws;
        int* bucket = cnt + cnt_ints;

        hipMemsetAsync(cnt, 0, N_NODES * sizeof(int), stream);
        hipMemsetAsync(out, 0, (size_t)out_size * sizeof(float), stream);

        lgc_bucket<<<N_EDGES / 256, 256, 0, stream>>>(
            src_idx, dst_idx, src_feats, cj, cnt, bucket, out);

        lgc_gather<<<(N_NODES * D_FEAT) / 256, 256, 0, stream>>>(
            src_feats, cj, ci, cnt, bucket, out);
    } else {
        // fallback: round-1 atomic scatter
        hipMemsetAsync(out, 0, (size_t)out_size * sizeof(float), stream);
        {
            const long total = (long)N_EDGES * 8;
            const int grid = (int)((total + 255) / 256);
            lgc_scatter<<<grid, 256, 0, stream>>>((const float4*)src_feats, cj,
                                                  src_idx, dst_idx, out);
        }
        {
            const int grid = (N_NODES * 8 + 255) / 256;
            lgc_scale<<<grid, 256, 0, stream>>>((float4*)out, ci);
        }
    }
}

// Round 3
// 206.081 us; speedup vs baseline: 3.5279x; 1.4044x over previous
//
#include <hip/hip_runtime.h>

#define N_NODES 100000
#define N_EDGES 1600000
#define D_FEAT 32
#define CAP 48                       // Poisson(16) max deg ~45; overflow path kept anyway
#define NPASS 16
#define NODES_PER_PASS ((N_NODES + NPASS - 1) / NPASS)      // 6250
#define THREADS_PER_PASS (N_EDGES / 4)                      // 400000 (4 edges/thread)
#define BLOCKS_PER_PASS ((THREADS_PER_PASS + 255) / 256)    // 1563

// ---- bucket build, dst-range multi-pass so the active bucket region is L2-resident ----
__global__ __launch_bounds__(256) void lgc_bucket(
    const int4*  __restrict__ dst4,      // [N_EDGES/4]
    const int4*  __restrict__ src4,      // [N_EDGES/4]
    const float* __restrict__ src_feats,
    const float* __restrict__ cj,
    int*         __restrict__ cnt,       // [N_NODES], pre-zeroed
    int*         __restrict__ bucket,    // [N_NODES * CAP]
    float*       __restrict__ out)       // pre-zeroed; overflow spill target
{
    int pass = blockIdx.x / BLOCKS_PER_PASS;
    int lb   = blockIdx.x % BLOCKS_PER_PASS;
    int t = lb * 256 + threadIdx.x;
    if (t >= THREADS_PER_PASS) return;

    const int lo = pass * NODES_PER_PASS;
    const int hi = lo + NODES_PER_PASS;

    int4 d4 = dst4[t];
    bool ix = (d4.x >= lo) & (d4.x < hi);
    bool iy = (d4.y >= lo) & (d4.y < hi);
    bool iz = (d4.z >= lo) & (d4.z < hi);
    bool iw = (d4.w >= lo) & (d4.w < hi);
    if (!(ix | iy | iz | iw)) return;

    int4 s4 = src4[t];
    int ds[4] = {d4.x, d4.y, d4.z, d4.w};
    int ss[4] = {s4.x, s4.y, s4.z, s4.w};
    bool in[4] = {ix, iy, iz, iw};

    #pragma unroll
    for (int k = 0; k < 4; ++k) {
        if (!in[k]) continue;
        int d = ds[k], s = ss[k];
        int pos = atomicAdd(&cnt[d], 1);
        if (pos < CAP) {
            bucket[(size_t)d * CAP + pos] = s;
        } else {
            // statistically-never overflow: spill directly into pre-zeroed out
            float c = cj[s];
            const float* row = src_feats + (size_t)s * D_FEAT;
            float* o = out + (size_t)d * D_FEAT;
            for (int f = 0; f < D_FEAT; ++f) atomicAdd(o + f, row[f] * c);
        }
    }
}

// ---- gather-sum: lane = (node, float4-slice); 4 bucket entries batched per int4 ----
__global__ __launch_bounds__(256) void lgc_gather(
    const float4* __restrict__ feats4,   // [N_NODES * 8]
    const float*  __restrict__ cj,
    const float*  __restrict__ ci,
    const int*    __restrict__ cnt,
    const int*    __restrict__ bucket,
    float4*       __restrict__ out4)     // [N_NODES * 8]
{
    int tid = blockIdx.x * 256 + threadIdx.x;  // exactly 800000
    int n = tid >> 3;
    int f = tid & 7;

    int c = cnt[n];
    if (c > CAP) c = CAP;
    const int4* b4 = (const int4*)(bucket + (size_t)n * CAP);

    float4 acc = make_float4(0.f, 0.f, 0.f, 0.f);
    for (int i = 0; i < c; i += 4) {
        int4 bv = b4[i >> 2];
        int m = c - i;
        {
            float w = cj[bv.x];
            float4 v = feats4[(size_t)bv.x * 8 + f];
            acc.x += v.x * w; acc.y += v.y * w; acc.z += v.z * w; acc.w += v.w * w;
        }
        if (m > 1) {
            float w = cj[bv.y];
            float4 v = feats4[(size_t)bv.y * 8 + f];
            acc.x += v.x * w; acc.y += v.y * w; acc.z += v.z * w; acc.w += v.w * w;
        }
        if (m > 2) {
            float w = cj[bv.z];
            float4 v = feats4[(size_t)bv.z * 8 + f];
            acc.x += v.x * w; acc.y += v.y * w; acc.z += v.z * w; acc.w += v.w * w;
        }
        if (m > 3) {
            float w = cj[bv.w];
            float4 v = feats4[(size_t)bv.w * 8 + f];
            acc.x += v.x * w; acc.y += v.y * w; acc.z += v.z * w; acc.w += v.w * w;
        }
    }

    float s = ci[n];
    float4 o = out4[tid];               // overflow spill (normally 0)
    acc.x = (acc.x + o.x) * s;
    acc.y = (acc.y + o.y) * s;
    acc.z = (acc.z + o.z) * s;
    acc.w = (acc.w + o.w) * s;
    out4[tid] = acc;
}

// ---------------- round-1 fallback path (only if ws too small) ----------------
__global__ __launch_bounds__(256) void lgc_scatter(
    const float4* __restrict__ src_feats4,
    const float*  __restrict__ cj,
    const int*    __restrict__ src_idx,
    const int*    __restrict__ dst_idx,
    float*        __restrict__ out)
{
    long tid = (long)blockIdx.x * blockDim.x + threadIdx.x;
    const long total = (long)N_EDGES * 8;
    if (tid >= total) return;
    int e  = (int)(tid >> 3);
    int f4 = (int)(tid & 7);
    int s = src_idx[e];
    int d = dst_idx[e];
    float c = cj[s];
    float4 v = src_feats4[s * 8 + f4];
    float* o = out + (size_t)d * D_FEAT + f4 * 4;
    atomicAdd(o + 0, v.x * c);
    atomicAdd(o + 1, v.y * c);
    atomicAdd(o + 2, v.z * c);
    atomicAdd(o + 3, v.w * c);
}

__global__ __launch_bounds__(256) void lgc_scale(
    float4*       __restrict__ out4,
    const float*  __restrict__ ci)
{
    int tid = blockIdx.x * blockDim.x + threadIdx.x;
    const int total = N_NODES * 8;
    if (tid >= total) return;
    float c = ci[tid >> 3];
    float4 v = out4[tid];
    v.x *= c; v.y *= c; v.z *= c; v.w *= c;
    out4[tid] = v;
}

extern "C" void kernel_launch(void* const* d_in, const int* in_sizes, int n_in,
                              void* d_out, int out_size, void* d_ws, size_t ws_size,
                              hipStream_t stream) {
    const float* src_feats = (const float*)d_in[0];   // [100000, 32] f32
    const float* cj        = (const float*)d_in[1];   // [100000, 1]
    const float* ci        = (const float*)d_in[2];   // [100000, 1]
    const int*   src_idx   = (const int*)d_in[3];     // [1600000]
    const int*   dst_idx   = (const int*)d_in[4];     // [1600000]
    float*       out       = (float*)d_out;           // [100000, 32] f32

    // ws layout: cnt[102400 ints] | bucket[N_NODES*CAP ints] (19.2 MB)
    const size_t cnt_ints    = 102400;
    const size_t bucket_ints = (size_t)N_NODES * CAP;
    const size_t need = (cnt_ints + bucket_ints) * sizeof(int);

    if (ws_size >= need) {
        int* cnt    = (int*)d_ws;
        int* bucket = cnt + cnt_ints;

        hipMemsetAsync(cnt, 0, N_NODES * sizeof(int), stream);
        hipMemsetAsync(out, 0, (size_t)out_size * sizeof(float), stream);

        lgc_bucket<<<NPASS * BLOCKS_PER_PASS, 256, 0, stream>>>(
            (const int4*)dst_idx, (const int4*)src_idx, src_feats, cj,
            cnt, bucket, out);

        lgc_gather<<<(N_NODES * 8) / 256, 256, 0, stream>>>(
            (const float4*)src_feats, cj, ci, cnt, bucket, (float4*)out);
    } else {
        hipMemsetAsync(out, 0, (size_t)out_size * sizeof(float), stream);
        {
            const long total = (long)N_EDGES * 8;
            const int grid = (int)((total + 255) / 256);
            lgc_scatter<<<grid, 256, 0, stream>>>((const float4*)src_feats, cj,
                                                  src_idx, dst_idx, out);
        }
        {
            const int grid = (N_NODES * 8 + 255) / 256;
            lgc_scale<<<grid, 256, 0, stream>>>((float4*)out, ci);
        }
    }
}

// Round 6
// 181.602 us; speedup vs baseline: 4.0034x; 1.1348x over previous
//
#include <hip/hip_runtime.h>

#define N_NODES 100000
#define N_EDGES 1600000
#define D_FEAT 32
#define CAP 32                        // Poisson(16): P(deg>32) ~1e-5 -> spill path
#define NXCD 8
#define NODES_PER_XCD (N_NODES / NXCD)            // 12500
#define EDGE_THREADS (N_EDGES / 4)                // 400000 (4 edges/thread)
#define EDGE_BLOCKS ((EDGE_THREADS + 255) / 256)  // 1563

// ---- bucket build: XCD x owns dst range [x*12500, (x+1)*12500).
// blockIdx%8 -> XCD round-robin mapping, so each bucket/cnt cache line is
// written by exactly ONE XCD's L2 -> full-line writeback, no cross-XCD
// partial-line amplification.
__global__ __launch_bounds__(256) void lgc_bucket(
    const int4*  __restrict__ dst4,      // [N_EDGES/4]
    const int4*  __restrict__ src4,      // [N_EDGES/4]
    const float* __restrict__ src_feats,
    const float* __restrict__ cj,
    int*         __restrict__ cnt,       // [N_NODES], pre-zeroed
    int*         __restrict__ bucket,    // [N_NODES * CAP]
    float*       __restrict__ out)       // pre-zeroed; overflow spill target
{
    int x  = blockIdx.x % NXCD;          // which dst-range this block handles
    int lb = blockIdx.x / NXCD;
    int t  = lb * 256 + threadIdx.x;
    if (t >= EDGE_THREADS) return;

    const int lo = x * NODES_PER_XCD;
    const int hi = lo + NODES_PER_XCD;

    int4 d4 = dst4[t];
    bool ix = (d4.x >= lo) & (d4.x < hi);
    bool iy = (d4.y >= lo) & (d4.y < hi);
    bool iz = (d4.z >= lo) & (d4.z < hi);
    bool iw = (d4.w >= lo) & (d4.w < hi);
    if (!(ix | iy | iz | iw)) return;

    int4 s4 = src4[t];
    int ds[4] = {d4.x, d4.y, d4.z, d4.w};
    int ss[4] = {s4.x, s4.y, s4.z, s4.w};
    bool in[4] = {ix, iy, iz, iw};

    #pragma unroll
    for (int k = 0; k < 4; ++k) {
        if (!in[k]) continue;
        int d = ds[k], s = ss[k];
        int pos = atomicAdd(&cnt[d], 1);
        if (pos < CAP) {
            bucket[(size_t)d * CAP + pos] = s;
        } else {
            // statistically-never overflow: spill into pre-zeroed out
            float c = cj[s];
            const float* row = src_feats + (size_t)s * D_FEAT;
            float* o = out + (size_t)d * D_FEAT;
            for (int f = 0; f < D_FEAT; ++f) atomicAdd(o + f, row[f] * c);
        }
    }
}

// ---- gather-sum: lane = (node, float4-slice); bucket row (8 int4) prefetched
// up-front, then 32 fully-unrolled predicated {cj, feat-row, fma} groups.
__global__ __launch_bounds__(256) void lgc_gather(
    const float4* __restrict__ feats4,   // [N_NODES * 8]
    const float*  __restrict__ cj,
    const float*  __restrict__ ci,
    const int*    __restrict__ cnt,
    const int*    __restrict__ bucket,
    float4*       __restrict__ out4)     // [N_NODES * 8]
{
    int tid = blockIdx.x * 256 + threadIdx.x;  // exactly 800000
    int n = tid >> 3;
    int f = tid & 7;

    int c = cnt[n];
    if (c > CAP) c = CAP;
    const int4* b4 = (const int4*)(bucket + (size_t)n * CAP);

    // Prefetch the whole bucket row: 8 independent int4 loads.
    int4 r[8];
    #pragma unroll
    for (int j = 0; j < 8; ++j)
        if (j * 4 < c) r[j] = b4[j];

    float4 acc = make_float4(0.f, 0.f, 0.f, 0.f);
    #pragma unroll
    for (int j = 0; j < 8; ++j) {
        int base = j * 4;
        if (base < c) {
            int4 bv = r[j];
            {
                float w = cj[bv.x];
                float4 v = feats4[(size_t)bv.x * 8 + f];
                acc.x += v.x * w; acc.y += v.y * w; acc.z += v.z * w; acc.w += v.w * w;
            }
            if (base + 1 < c) {
                float w = cj[bv.y];
                float4 v = feats4[(size_t)bv.y * 8 + f];
                acc.x += v.x * w; acc.y += v.y * w; acc.z += v.z * w; acc.w += v.w * w;
            }
            if (base + 2 < c) {
                float w = cj[bv.z];
                float4 v = feats4[(size_t)bv.z * 8 + f];
                acc.x += v.x * w; acc.y += v.y * w; acc.z += v.z * w; acc.w += v.w * w;
            }
            if (base + 3 < c) {
                float w = cj[bv.w];
                float4 v = feats4[(size_t)bv.w * 8 + f];
                acc.x += v.x * w; acc.y += v.y * w; acc.z += v.z * w; acc.w += v.w * w;
            }
        }
    }

    float s = ci[n];
    float4 o = out4[tid];               // overflow spill (normally 0)
    acc.x = (acc.x + o.x) * s;
    acc.y = (acc.y + o.y) * s;
    acc.z = (acc.z + o.z) * s;
    acc.w = (acc.w + o.w) * s;
    out4[tid] = acc;
}

// ---------------- round-1 fallback path (only if ws too small) ----------------
__global__ __launch_bounds__(256) void lgc_scatter(
    const float4* __restrict__ src_feats4,
    const float*  __restrict__ cj,
    const int*    __restrict__ src_idx,
    const int*    __restrict__ dst_idx,
    float*        __restrict__ out)
{
    long tid = (long)blockIdx.x * blockDim.x + threadIdx.x;
    const long total = (long)N_EDGES * 8;
    if (tid >= total) return;
    int e  = (int)(tid >> 3);
    int f4 = (int)(tid & 7);
    int s = src_idx[e];
    int d = dst_idx[e];
    float c = cj[s];
    float4 v = src_feats4[s * 8 + f4];
    float* o = out + (size_t)d * D_FEAT + f4 * 4;
    atomicAdd(o + 0, v.x * c);
    atomicAdd(o + 1, v.y * c);
    atomicAdd(o + 2, v.z * c);
    atomicAdd(o + 3, v.w * c);
}

__global__ __launch_bounds__(256) void lgc_scale(
    float4*       __restrict__ out4,
    const float*  __restrict__ ci)
{
    int tid = blockIdx.x * blockDim.x + threadIdx.x;
    const int total = N_NODES * 8;
    if (tid >= total) return;
    float c = ci[tid >> 3];
    float4 v = out4[tid];
    v.x *= c; v.y *= c; v.z *= c; v.w *= c;
    out4[tid] = v;
}

extern "C" void kernel_launch(void* const* d_in, const int* in_sizes, int n_in,
                              void* d_out, int out_size, void* d_ws, size_t ws_size,
                              hipStream_t stream) {
    const float* src_feats = (const float*)d_in[0];   // [100000, 32] f32
    const float* cj        = (const float*)d_in[1];   // [100000, 1]
    const float* ci        = (const float*)d_in[2];   // [100000, 1]
    const int*   src_idx   = (const int*)d_in[3];     // [1600000]
    const int*   dst_idx   = (const int*)d_in[4];     // [1600000]
    float*       out       = (float*)d_out;           // [100000, 32] f32

    // ws layout: cnt[102400 ints] | bucket[N_NODES*CAP ints] (12.8 MB)
    const size_t cnt_ints    = 102400;
    const size_t bucket_ints = (size_t)N_NODES * CAP;
    const size_t need = (cnt_ints + bucket_ints) * sizeof(int);

    if (ws_size >= need) {
        int* cnt    = (int*)d_ws;
        int* bucket = cnt + cnt_ints;

        hipMemsetAsync(cnt, 0, N_NODES * sizeof(int), stream);
        hipMemsetAsync(out, 0, (size_t)out_size * sizeof(float), stream);

        lgc_bucket<<<NXCD * EDGE_BLOCKS, 256, 0, stream>>>(
            (const int4*)dst_idx, (const int4*)src_idx, src_feats, cj,
            cnt, bucket, out);

        lgc_gather<<<(N_NODES * 8) / 256, 256, 0, stream>>>(
            (const float4*)src_feats, cj, ci, cnt, bucket, (float4*)out);
    } else {
        hipMemsetAsync(out, 0, (size_t)out_size * sizeof(float), stream);
        {
            const long total = (long)N_EDGES * 8;
            const int grid = (int)((total + 255) / 256);
            lgc_scatter<<<grid, 256, 0, stream>>>((const float4*)src_feats, cj,
                                                  src_idx, dst_idx, out);
        }
        {
            const int grid = (N_NODES * 8 + 255) / 256;
            lgc_scale<<<grid, 256, 0, stream>>>((float4*)out, ci);
        }
    }
}